// Round 4
// baseline (950.862 us; speedup 1.0000x reference)
//
#include <hip/hip_runtime.h>
#include <stdint.h>

typedef __attribute__((ext_vector_type(8))) short bhalf8;   // 8 bf16 (4 VGPR)
typedef __attribute__((ext_vector_type(4))) float floatx4;  // 4 f32 acc

#define BM 256
#define BN 128
#define BK 64
#define AST (BK + 8)   // 72 elems = 144B stride: bank=(4*row+c)%32 -> <=2-way (free)
#define BST (BK + 8)
#define NT 512

constexpr int Mdim = 8192;   // B*S
constexpr int Ndim = 11008;
constexpr int Kdim = 4096;

// packed f32x2 -> bf16x2 (RNE), single VALU inst. Any src0/src1->half ordering
// quirk cancels: the same k^1 permutation is applied to A and B fragments.
__device__ __forceinline__ unsigned int cvt_pk_bf16(float lo, float hi) {
  unsigned int r;
  asm("v_cvt_pk_bf16_f32 %0, %1, %2" : "=v"(r) : "v"(lo), "v"(hi));
  return r;
}

__global__ __launch_bounds__(NT, 1)
void qgemm_kernel(const float*         __restrict__ x,       // f32 (M,K)  [fp16 upcast]
                  const unsigned int*  __restrict__ qweight, // (K/8, N) int32
                  const unsigned int*  __restrict__ qzeros,  // (G, N/8) int32
                  const float*         __restrict__ scales,  // f32 (G,N)  [fp16 upcast]
                  const float*         __restrict__ bias,    // f32 (N)    [fp16 upcast]
                  float*               __restrict__ out)     // f32 (M,N)  <-- THE FIX
{
  __shared__ unsigned short As[BM * AST];   // 36864 B
  __shared__ unsigned short Bs[BN * BST];   // 18432 B  (total 55296 B)

  const int tid  = threadIdx.x;
  const int lane = tid & 63;
  const int wid  = tid >> 6;        // 0..7
  const int wm   = wid >> 1;        // 0..3 (m sub-tile)
  const int wn   = wid & 1;         // 0..1 (n sub-tile)
  const int fr   = lane & 15;
  const int kh   = lane >> 4;       // 0..3

  // Bijective XCD swizzle (nwg = 2752, % 8 == 0). Consecutive swz on one XCD
  // share the same A m-panel for 86 blocks -> A L2-resident per XCD.
  const int nbn = Ndim / BN;                    // 86
  const int nwg = (Mdim / BM) * nbn;            // 2752
  const int bid = blockIdx.x;
  const int swz = (bid & 7) * (nwg >> 3) + (bid >> 3);
  const int m0  = (swz / nbn) * BM;
  const int n0  = (swz % nbn) * BN;

  // A staging: 4 row-chunks/thread; chunk i: row ar+i*64, f32 cols ac..ac+7
  const int ar = tid >> 3;                 // 0..63
  const int ac = (tid & 7) * 8;            // 0,8,..,56
  const float* xbase = x + (size_t)(m0 + ar) * Kdim + ac;

  // B staging: 2 int32/thread, same column nn (shared scale/zero)
  const int bc = tid & 127;                // n within tile
  const int br = tid >> 7;                 // 0..3; second row = br+4
  const int nn = n0 + bc;

  floatx4 acc[4][4] = {};

  for (int kt = 0; kt < Kdim / BK; ++kt) {
    const int k0 = kt * BK;
    __syncthreads();   // previous tile's ds_reads complete before overwrite

    // ---- global loads into registers ----
    float4 av[4][2];
#pragma unroll
    for (int i = 0; i < 4; ++i) {
      const float* p = xbase + (size_t)i * 64 * Kdim + k0;
      av[i][0] = *(const float4*)(p);
      av[i][1] = *(const float4*)(p + 4);
    }

    const int g = k0 >> 7;   // GROUPSIZE=128, uniform within K-tile
    const float        s  = scales[(size_t)g * Ndim + nn];
    const unsigned int qz = qzeros[(size_t)g * (Ndim / 8) + (nn >> 3)];
    const float        zc = -(float)((qz >> ((nn & 7) * 4)) & 15u) * s;
    unsigned int qv[2];
    qv[0] = qweight[(size_t)(k0 / 8 + br)     * Ndim + nn];
    qv[1] = qweight[(size_t)(k0 / 8 + br + 4) * Ndim + nn];

    // ---- LDS writes: A converted f32->bf16, B dequanted to B^T [n][k] ----
#pragma unroll
    for (int i = 0; i < 4; ++i) {
      uint4 pk;
      pk.x = cvt_pk_bf16(av[i][0].x, av[i][0].y);
      pk.y = cvt_pk_bf16(av[i][0].z, av[i][0].w);
      pk.z = cvt_pk_bf16(av[i][1].x, av[i][1].y);
      pk.w = cvt_pk_bf16(av[i][1].z, av[i][1].w);
      *(uint4*)(&As[(ar + i * 64) * AST + ac]) = pk;   // ds_write_b128
    }

#pragma unroll
    for (int i = 0; i < 2; ++i) {
      const unsigned int q = qv[i];
      const int r = br + i * 4;            // k-octet within tile
      uint4 pk;
      unsigned int w[4];
#pragma unroll
      for (int j = 0; j < 4; ++j) {
        const float f0 = fmaf((float)((q >> (8 * j))     & 15u), s, zc); // k=8r+2j
        const float f1 = fmaf((float)((q >> (8 * j + 4)) & 15u), s, zc); // k=8r+2j+1
        w[j] = cvt_pk_bf16(f0, f1);
      }
      pk.x = w[0]; pk.y = w[1]; pk.z = w[2]; pk.w = w[3];
      *(uint4*)(&Bs[bc * BST + r * 8]) = pk;   // ds_write_b128
    }
    __syncthreads();

    // ---- MFMA: 2 k-steps x 16 = 32 MFMA/wave per K-tile ----
#pragma unroll
    for (int ks = 0; ks < BK / 32; ++ks) {
      bhalf8 a[4], b[4];
#pragma unroll
      for (int mi = 0; mi < 4; ++mi)
        a[mi] = *(const bhalf8*)(&As[(wm * 64 + mi * 16 + fr) * AST + ks * 32 + kh * 8]);
#pragma unroll
      for (int ni = 0; ni < 4; ++ni)
        b[ni] = *(const bhalf8*)(&Bs[(wn * 64 + ni * 16 + fr) * BST + ks * 32 + kh * 8]);
#pragma unroll
      for (int mi = 0; mi < 4; ++mi)
#pragma unroll
        for (int ni = 0; ni < 4; ++ni)
          acc[mi][ni] = __builtin_amdgcn_mfma_f32_16x16x32_bf16(a[mi], b[ni], acc[mi][ni], 0, 0, 0);
    }
  }

  // ---- epilogue: +bias, store FLOAT32 (C/D map: col=lane&15, row=kh*4+e) ----
#pragma unroll
  for (int ni = 0; ni < 4; ++ni) {
    const int col = n0 + wn * 64 + ni * 16 + fr;
    const float bsv = bias[col];
#pragma unroll
    for (int mi = 0; mi < 4; ++mi) {
      const int rowb = m0 + wm * 64 + mi * 16 + kh * 4;
#pragma unroll
      for (int e = 0; e < 4; ++e)
        out[(size_t)(rowb + e) * Ndim + col] = acc[mi][ni][e] + bsv;
    }
  }
}

extern "C" void kernel_launch(void* const* d_in, const int* in_sizes, int n_in,
                              void* d_out, int out_size, void* d_ws, size_t ws_size,
                              hipStream_t stream) {
  const float*        x       = (const float*)d_in[0];
  const unsigned int* qweight = (const unsigned int*)d_in[1];
  const unsigned int* qzeros  = (const unsigned int*)d_in[2];
  const float*        scales  = (const float*)d_in[3];
  // d_in[4] = g_idx: arange(K)//128, recomputed in-kernel as k>>7
  const float*        bias    = (const float*)d_in[5];
  float*              outp    = (float*)d_out;

  const int nwg = (Mdim / BM) * (Ndim / BN);   // 2752
  qgemm_kernel<<<dim3(nwg), dim3(NT), 0, stream>>>(x, qweight, qzeros, scales, bias, outp);
}